// Round 8
// baseline (215.167 us; speedup 1.0000x reference)
//
#include <hip/hip_runtime.h>
#include <math.h>

#define B_ 32
#define C_ 256
#define HW_ 3136      // 56*56
#define HW4_ 784      // HW/4 (float4 chunks); 784 = 3*256 + 16
#define G_ 32
#define EPS_ 1e-5f

typedef float v4f __attribute__((ext_vector_type(4)));

// ws layout (floats):
//   [0 .. 8191]       zpart[b*C + c] = planesum(b,c) * alpha_w[c] / HW   (K1 -> K1.5)
//   [8192 .. 8447]    gs[c]
//   [8448 .. 8703]    gsh[c]
//   [8704 .. 8959]    dsc[c] = ms[c]  - gs[c]
//   [8960 .. 9215]    dsh[c] = msh[c] - gsh[c]
//   [9216 .. 25599]   scsh[b*C + c] = float2{sc, sh}   (K1.5 -> K2)
#define WS_Z    0
#define WS_GS   8192
#define WS_GSH  8448
#define WS_DSC  8704
#define WS_DSH  8960
#define WS_SCSH 9216

// K1: one block per (b,c) plane. Pool the plane, fold alpha_w into the sum,
// single non-atomic store. Blocks bc<256 additionally fold the
// batch-independent affine params for channel c.
__global__ __launch_bounds__(256) void pool_kernel(
    const float* __restrict__ x, const float* __restrict__ alpha_w,
    const float* __restrict__ g_w, const float* __restrict__ g_b,
    const float* __restrict__ g_rm, const float* __restrict__ g_rv,
    const float* __restrict__ grp_w, const float* __restrict__ grp_b,
    const float* __restrict__ grp_rm, const float* __restrict__ grp_rv,
    float* __restrict__ ws)
{
    const int bc = blockIdx.x;
    const int c  = bc & (C_ - 1);
    const int tid = threadIdx.x;
    const int lane = tid & 63, wv = tid >> 6;
    const v4f* __restrict__ px = (const v4f*)(x + (size_t)bc * HW_);

    v4f a0 = px[tid];
    v4f a1 = px[tid + 256];
    v4f a2 = px[tid + 512];
    float s = a0.x + a0.y + a0.z + a0.w
            + a1.x + a1.y + a1.z + a1.w
            + a2.x + a2.y + a2.z + a2.w;
    if (tid < 16) {
        v4f a3 = px[tid + 768];
        s += a3.x + a3.y + a3.z + a3.w;
    }
    #pragma unroll
    for (int off = 32; off; off >>= 1) s += __shfl_down(s, off);
    __shared__ float red[4];
    if (lane == 0) red[wv] = s;
    __syncthreads();
    if (tid == 0)
        ws[WS_Z + bc] = (red[0] + red[1] + red[2] + red[3])
                        * (alpha_w[c] * (1.f / HW_));

    // batch-independent param fold: lanes 0..63, g = lane&31 (upper half redundant)
    if (bc < C_ && tid < 64) {
        const int g = tid & 31;
        float sg  = grp_w[g * C_ + c] * rsqrtf(grp_rv[g * C_ + c] + EPS_);
        float shv = grp_b[g * C_ + c] - grp_rm[g * C_ + c] * sg;
        #pragma unroll
        for (int off = 16; off; off >>= 1) {
            sg  += __shfl_down(sg, off);
            shv += __shfl_down(shv, off);
        }
        if (tid == 0) {   // lane0 = sum over groups 0..31
            float msv  = sg  * (1.f / G_);
            float mshv = shv * (1.f / G_);
            float gsv  = g_w[c] * rsqrtf(g_rv[c] + EPS_);
            float gshv = g_b[c] - g_rm[c] * gsv;
            ws[WS_GS  + c] = gsv;
            ws[WS_GSH + c] = gshv;
            ws[WS_DSC + c] = msv  - gsv;
            ws[WS_DSH + c] = mshv - gshv;
        }
    }
}

// K1.5: one block per image. alpha[b] = sigmoid(sum of pre-folded zpart row),
// then thread c emits the FINAL per-(b,c) scale/shift pair. 32 blocks, ~2 us.
__global__ __launch_bounds__(256) void alpha_kernel(
    float* __restrict__ ws, const float* __restrict__ alpha_b)
{
    const int b = blockIdx.x, tid = threadIdx.x;
    const int lane = tid & 63, wv = tid >> 6;
    float s = ws[WS_Z + b * C_ + tid];
    #pragma unroll
    for (int off = 32; off; off >>= 1) s += __shfl_down(s, off);
    __shared__ float red[4];
    __shared__ float a_sh;
    if (lane == 0) red[wv] = s;
    __syncthreads();
    if (tid == 0) {
        float z = red[0] + red[1] + red[2] + red[3] + alpha_b[0];
        a_sh = 1.f / (1.f + __expf(-z));
    }
    __syncthreads();
    const float a = a_sh;
    const int c = tid;
    float2 ss;
    ss.x = fmaf(a, ws[WS_DSC + c], ws[WS_GS  + c]);   // (1-a)*gs + a*ms
    ss.y = fmaf(a, ws[WS_DSH + c], ws[WS_GSH + c]);
    ((float2*)(ws + WS_SCSH))[b * C_ + c] = ss;
}

// K2: pure stream. One block-uniform 8B scalar load, 3 float4 loads,
// 3 fma quads, 3 nt stores. No LDS, no syncthreads, no shuffles.
__global__ __launch_bounds__(256) void apply_kernel(
    const float* __restrict__ x, const float* __restrict__ ws,
    float* __restrict__ out)
{
    const int bc = blockIdx.x;
    const int tid = threadIdx.x;
    const float2 ss = ((const float2*)(ws + WS_SCSH))[bc];   // s_load_dwordx2
    const float sc = ss.x, sh = ss.y;
    const v4f* __restrict__ px = (const v4f*)(x + (size_t)bc * HW_);
    v4f* __restrict__ po = (v4f*)(out + (size_t)bc * HW_);

    v4f a0 = px[tid];
    v4f a1 = px[tid + 256];
    v4f a2 = px[tid + 512];
    v4f a3;
    if (tid < 16) a3 = px[tid + 768];

    v4f r;
    r.x = fmaf(a0.x, sc, sh); r.y = fmaf(a0.y, sc, sh);
    r.z = fmaf(a0.z, sc, sh); r.w = fmaf(a0.w, sc, sh);
    __builtin_nontemporal_store(r, &po[tid]);
    r.x = fmaf(a1.x, sc, sh); r.y = fmaf(a1.y, sc, sh);
    r.z = fmaf(a1.z, sc, sh); r.w = fmaf(a1.w, sc, sh);
    __builtin_nontemporal_store(r, &po[tid + 256]);
    r.x = fmaf(a2.x, sc, sh); r.y = fmaf(a2.y, sc, sh);
    r.z = fmaf(a2.z, sc, sh); r.w = fmaf(a2.w, sc, sh);
    __builtin_nontemporal_store(r, &po[tid + 512]);
    if (tid < 16) {
        r.x = fmaf(a3.x, sc, sh); r.y = fmaf(a3.y, sc, sh);
        r.z = fmaf(a3.z, sc, sh); r.w = fmaf(a3.w, sc, sh);
        __builtin_nontemporal_store(r, &po[tid + 768]);
    }
}

extern "C" void kernel_launch(void* const* d_in, const int* in_sizes, int n_in,
                              void* d_out, int out_size, void* d_ws, size_t ws_size,
                              hipStream_t stream) {
    const float* x       = (const float*)d_in[0];
    const float* alpha_w = (const float*)d_in[2];
    const float* alpha_b = (const float*)d_in[3];
    const float* g_w     = (const float*)d_in[4];
    const float* g_b     = (const float*)d_in[5];
    const float* g_rm    = (const float*)d_in[6];
    const float* g_rv    = (const float*)d_in[7];
    const float* grp_w   = (const float*)d_in[8];
    const float* grp_b   = (const float*)d_in[9];
    const float* grp_rm  = (const float*)d_in[10];
    const float* grp_rv  = (const float*)d_in[11];
    float* out = (float*)d_out;
    float* ws  = (float*)d_ws;

    pool_kernel<<<B_ * C_, 256, 0, stream>>>(x, alpha_w,
                                             g_w, g_b, g_rm, g_rv,
                                             grp_w, grp_b, grp_rm, grp_rv, ws);
    alpha_kernel<<<B_, 256, 0, stream>>>(ws, alpha_b);
    apply_kernel<<<B_ * C_, 256, 0, stream>>>(x, ws, out);
}

// Round 9
// 214.979 us; speedup vs baseline: 1.0009x; 1.0009x over previous
//
#include <hip/hip_runtime.h>
#include <math.h>

#define B_ 32
#define C_ 256
#define HW_ 3136      // 56*56
#define HW4_ 784      // HW/4 (float4 chunks); 784 = 3*256 + 16
#define G_ 32
#define EPS_ 1e-5f

#define PPB_ 4        // planes per block
#define NBLK_ 2048    // (B_*C_)/PPB_

typedef float v4f __attribute__((ext_vector_type(4)));

// ws layout (floats):
//   [0 .. 8191]      zpart[b*C + c] = planesum(b,c) * alpha_w[c] / HW   (K1 -> K2)
//   [8192 .. 8447]   gs[c]
//   [8448 .. 8703]   gsh[c]
//   [8704 .. 8959]   dsc[c] = ms[c]  - gs[c]
//   [8960 .. 9215]   dsh[c] = msh[c] - gsh[c]
#define WS_Z    0
#define WS_GS   8192
#define WS_GSH  8448
#define WS_DSC  8704
#define WS_DSH  8960

// K1: 2048 long-lived blocks, 4 consecutive planes each. Pool each plane,
// fold alpha_w into the sum, non-atomic store. Blocks 0..63 (image 0) also
// fold the batch-independent params: wave wv handles channel p0+wv.
__global__ __launch_bounds__(256) void pool_kernel(
    const float* __restrict__ x, const float* __restrict__ alpha_w,
    const float* __restrict__ g_w, const float* __restrict__ g_b,
    const float* __restrict__ g_rm, const float* __restrict__ g_rv,
    const float* __restrict__ grp_w, const float* __restrict__ grp_b,
    const float* __restrict__ grp_rm, const float* __restrict__ grp_rv,
    float* __restrict__ ws)
{
    const int bid = blockIdx.x;
    const int tid = threadIdx.x;
    const int lane = tid & 63, wv = tid >> 6;
    const int p0 = bid * PPB_;

    float s[PPB_];
    #pragma unroll
    for (int k = 0; k < PPB_; ++k) {
        const v4f* __restrict__ px = (const v4f*)(x + (size_t)(p0 + k) * HW_);
        v4f a0 = px[tid];
        v4f a1 = px[tid + 256];
        v4f a2 = px[tid + 512];
        float st = a0.x + a0.y + a0.z + a0.w
                 + a1.x + a1.y + a1.z + a1.w
                 + a2.x + a2.y + a2.z + a2.w;
        if (tid < 16) {
            v4f a3 = px[tid + 768];
            st += a3.x + a3.y + a3.z + a3.w;
        }
        s[k] = st;
    }

    __shared__ float red[4][PPB_];
    #pragma unroll
    for (int k = 0; k < PPB_; ++k) {
        float st = s[k];
        #pragma unroll
        for (int off = 32; off; off >>= 1) st += __shfl_down(st, off);
        if (lane == 0) red[wv][k] = st;
    }
    __syncthreads();
    if (tid < PPB_) {
        const int bc = p0 + tid;
        const int c  = bc & (C_ - 1);
        ws[WS_Z + bc] = (red[0][tid] + red[1][tid] + red[2][tid] + red[3][tid])
                        * (alpha_w[c] * (1.f / HW_));
    }

    // batch-independent param fold: blocks 0..63 cover c = 0..255, one wave each
    if (bid < (C_ / PPB_)) {
        const int c = p0 + wv;          // wave wv -> channel p0+wv
        const int g = lane & 31;
        float sg  = grp_w[g * C_ + c] * rsqrtf(grp_rv[g * C_ + c] + EPS_);
        float shv = grp_b[g * C_ + c] - grp_rm[g * C_ + c] * sg;
        #pragma unroll
        for (int off = 16; off; off >>= 1) {
            sg  += __shfl_down(sg, off);
            shv += __shfl_down(shv, off);
        }
        if (lane == 0) {
            float msv  = sg  * (1.f / G_);
            float mshv = shv * (1.f / G_);
            float gsv  = g_w[c] * rsqrtf(g_rv[c] + EPS_);
            float gshv = g_b[c] - g_rm[c] * gsv;
            ws[WS_GS  + c] = gsv;
            ws[WS_GSH + c] = gshv;
            ws[WS_DSC + c] = msv  - gsv;
            ws[WS_DSH + c] = mshv - gshv;
        }
    }
}

// K2: 2048 long-lived blocks, 4 consecutive planes each (same image).
// All bulk x loads issued first; alpha prologue (once per block, amortized 4x)
// runs under them; then 4 planes of fma + nt-store stream.
__global__ __launch_bounds__(256) void apply_kernel(
    const float* __restrict__ x, const float* __restrict__ ws,
    const float* __restrict__ alpha_b, float* __restrict__ out)
{
    const int bid = blockIdx.x;
    const int tid = threadIdx.x;
    const int lane = tid & 63, wv = tid >> 6;
    const int p0 = bid * PPB_;
    const int b  = p0 >> 8;            // 4 consecutive planes -> one image
    const int c0 = p0 & (C_ - 1);

    // issue all bulk loads first (12 x v4f + 4 tails): latency under prologue
    v4f va[PPB_][3];
    v4f vt[PPB_];
    #pragma unroll
    for (int k = 0; k < PPB_; ++k) {
        const v4f* __restrict__ px = (const v4f*)(x + (size_t)(p0 + k) * HW_);
        va[k][0] = px[tid];
        va[k][1] = px[tid + 256];
        va[k][2] = px[tid + 512];
        if (tid < 16) vt[k] = px[tid + 768];
    }

    // alpha[b]: reduce the pre-folded row zpart[b,:]
    float s = ws[WS_Z + b * C_ + tid];
    #pragma unroll
    for (int off = 32; off; off >>= 1) s += __shfl_down(s, off);
    __shared__ float red[4];
    __shared__ float a_sh;
    if (lane == 0) red[wv] = s;
    __syncthreads();
    if (tid == 0) {
        float z = red[0] + red[1] + red[2] + red[3] + alpha_b[0];
        a_sh = 1.f / (1.f + __expf(-z));
    }
    __syncthreads();
    const float a = a_sh;

    #pragma unroll
    for (int k = 0; k < PPB_; ++k) {
        const int c = c0 + k;
        const float sc = fmaf(a, ws[WS_DSC + c], ws[WS_GS  + c]);  // (1-a)gs + a*ms
        const float sh = fmaf(a, ws[WS_DSH + c], ws[WS_GSH + c]);
        v4f* __restrict__ po = (v4f*)(out + (size_t)(p0 + k) * HW_);

        v4f r;
        r.x = fmaf(va[k][0].x, sc, sh); r.y = fmaf(va[k][0].y, sc, sh);
        r.z = fmaf(va[k][0].z, sc, sh); r.w = fmaf(va[k][0].w, sc, sh);
        __builtin_nontemporal_store(r, &po[tid]);
        r.x = fmaf(va[k][1].x, sc, sh); r.y = fmaf(va[k][1].y, sc, sh);
        r.z = fmaf(va[k][1].z, sc, sh); r.w = fmaf(va[k][1].w, sc, sh);
        __builtin_nontemporal_store(r, &po[tid + 256]);
        r.x = fmaf(va[k][2].x, sc, sh); r.y = fmaf(va[k][2].y, sc, sh);
        r.z = fmaf(va[k][2].z, sc, sh); r.w = fmaf(va[k][2].w, sc, sh);
        __builtin_nontemporal_store(r, &po[tid + 512]);
        if (tid < 16) {
            r.x = fmaf(vt[k].x, sc, sh); r.y = fmaf(vt[k].y, sc, sh);
            r.z = fmaf(vt[k].z, sc, sh); r.w = fmaf(vt[k].w, sc, sh);
            __builtin_nontemporal_store(r, &po[tid + 768]);
        }
    }
}

extern "C" void kernel_launch(void* const* d_in, const int* in_sizes, int n_in,
                              void* d_out, int out_size, void* d_ws, size_t ws_size,
                              hipStream_t stream) {
    const float* x       = (const float*)d_in[0];
    const float* alpha_w = (const float*)d_in[2];
    const float* alpha_b = (const float*)d_in[3];
    const float* g_w     = (const float*)d_in[4];
    const float* g_b     = (const float*)d_in[5];
    const float* g_rm    = (const float*)d_in[6];
    const float* g_rv    = (const float*)d_in[7];
    const float* grp_w   = (const float*)d_in[8];
    const float* grp_b   = (const float*)d_in[9];
    const float* grp_rm  = (const float*)d_in[10];
    const float* grp_rv  = (const float*)d_in[11];
    float* out = (float*)d_out;
    float* ws  = (float*)d_ws;

    pool_kernel<<<NBLK_, 256, 0, stream>>>(x, alpha_w,
                                           g_w, g_b, g_rm, g_rv,
                                           grp_w, grp_b, grp_rm, grp_rv, ws);
    apply_kernel<<<NBLK_, 256, 0, stream>>>(x, ws, alpha_b, out);
}

// Round 10
// 211.312 us; speedup vs baseline: 1.0182x; 1.0174x over previous
//
#include <hip/hip_runtime.h>
#include <math.h>

#define B_ 32
#define C_ 256
#define HW_ 3136      // 56*56
#define HW4_ 784      // HW/4 (float4 chunks); 784 = 3*256 + 16
#define G_ 32
#define EPS_ 1e-5f

typedef float v4f __attribute__((ext_vector_type(4)));

// ws layout (floats):
//   [0 .. 8191]      zpart[b*C + c] = planesum(b,c) * alpha_w[c] / HW   (K1 -> K2)
//   [8192 .. 8447]   gs[c]
//   [8448 .. 8703]   gsh[c]
//   [8704 .. 8959]   dsc[c] = ms[c]  - gs[c]
//   [8960 .. 9215]   dsh[c] = msh[c] - gsh[c]
#define WS_Z    0
#define WS_GS   8192
#define WS_GSH  8448
#define WS_DSC  8704
#define WS_DSH  8960

// K1: one block per (b,c) plane. Pool the plane, fold alpha_w into the sum,
// single non-atomic store. Blocks bc<256 additionally fold the
// batch-independent affine params for channel c. NORMAL loads (must
// populate L3 for K2's re-read).
__global__ __launch_bounds__(256) void pool_kernel(
    const float* __restrict__ x, const float* __restrict__ alpha_w,
    const float* __restrict__ g_w, const float* __restrict__ g_b,
    const float* __restrict__ g_rm, const float* __restrict__ g_rv,
    const float* __restrict__ grp_w, const float* __restrict__ grp_b,
    const float* __restrict__ grp_rm, const float* __restrict__ grp_rv,
    float* __restrict__ ws)
{
    const int bc = blockIdx.x;
    const int c  = bc & (C_ - 1);
    const int tid = threadIdx.x;
    const int lane = tid & 63, wv = tid >> 6;
    const v4f* __restrict__ px = (const v4f*)(x + (size_t)bc * HW_);

    v4f a0 = px[tid];
    v4f a1 = px[tid + 256];
    v4f a2 = px[tid + 512];
    float s = a0.x + a0.y + a0.z + a0.w
            + a1.x + a1.y + a1.z + a1.w
            + a2.x + a2.y + a2.z + a2.w;
    if (tid < 16) {
        v4f a3 = px[tid + 768];
        s += a3.x + a3.y + a3.z + a3.w;
    }
    #pragma unroll
    for (int off = 32; off; off >>= 1) s += __shfl_down(s, off);
    __shared__ float red[4];
    if (lane == 0) red[wv] = s;
    __syncthreads();
    if (tid == 0)
        ws[WS_Z + bc] = (red[0] + red[1] + red[2] + red[3])
                        * (alpha_w[c] * (1.f / HW_));

    // batch-independent param fold: lanes 0..63, g = lane&31 (upper half redundant)
    if (bc < C_ && tid < 64) {
        const int g = tid & 31;
        float sg  = grp_w[g * C_ + c] * rsqrtf(grp_rv[g * C_ + c] + EPS_);
        float shv = grp_b[g * C_ + c] - grp_rm[g * C_ + c] * sg;
        #pragma unroll
        for (int off = 16; off; off >>= 1) {
            sg  += __shfl_down(sg, off);
            shv += __shfl_down(shv, off);
        }
        if (tid == 0) {   // lane0 = sum over groups 0..31
            float msv  = sg  * (1.f / G_);
            float mshv = shv * (1.f / G_);
            float gsv  = g_w[c] * rsqrtf(g_rv[c] + EPS_);
            float gshv = g_b[c] - g_rm[c] * gsv;
            ws[WS_GS  + c] = gsv;
            ws[WS_GSH + c] = gshv;
            ws[WS_DSC + c] = msv  - gsv;
            ws[WS_DSH + c] = mshv - gshv;
        }
    }
}

// K2: one block per (b,c) plane. x loads NONTEMPORAL (consume-once, L3-hot:
// don't allocate in L2 -> keep the L2 interface clear for the store stream).
// Loads issued before the prologue; alpha = single coalesced row-reduce of
// the pre-folded dot; then fma + nt-store stream.
__global__ __launch_bounds__(256) void apply_kernel(
    const float* __restrict__ x, const float* __restrict__ ws,
    const float* __restrict__ alpha_b, float* __restrict__ out)
{
    const int bc = blockIdx.x;
    const int c  = bc & (C_ - 1);
    const int b  = bc >> 8;
    const int tid = threadIdx.x;
    const int lane = tid & 63, wv = tid >> 6;
    const v4f* __restrict__ px = (const v4f*)(x + (size_t)bc * HW_);
    v4f* __restrict__ po = (v4f*)(out + (size_t)bc * HW_);

    // issue the bulk x loads first (latency overlap with the prologue)
    v4f a0 = __builtin_nontemporal_load(&px[tid]);
    v4f a1 = __builtin_nontemporal_load(&px[tid + 256]);
    v4f a2 = __builtin_nontemporal_load(&px[tid + 512]);
    v4f a3;
    if (tid < 16) a3 = __builtin_nontemporal_load(&px[tid + 768]);

    // alpha[b]: reduce the pre-folded row zpart[b,:]
    float s = ws[WS_Z + b * C_ + tid];
    #pragma unroll
    for (int off = 32; off; off >>= 1) s += __shfl_down(s, off);
    __shared__ float red[4];
    __shared__ float a_sh;
    if (lane == 0) red[wv] = s;
    __syncthreads();
    if (tid == 0) {
        float z = red[0] + red[1] + red[2] + red[3] + alpha_b[0];
        a_sh = 1.f / (1.f + __expf(-z));
    }
    __syncthreads();
    const float a = a_sh;

    const float sc = fmaf(a, ws[WS_DSC + c], ws[WS_GS  + c]);  // (1-a)gs + a*ms
    const float sh = fmaf(a, ws[WS_DSH + c], ws[WS_GSH + c]);

    v4f r;
    r.x = fmaf(a0.x, sc, sh); r.y = fmaf(a0.y, sc, sh);
    r.z = fmaf(a0.z, sc, sh); r.w = fmaf(a0.w, sc, sh);
    __builtin_nontemporal_store(r, &po[tid]);
    r.x = fmaf(a1.x, sc, sh); r.y = fmaf(a1.y, sc, sh);
    r.z = fmaf(a1.z, sc, sh); r.w = fmaf(a1.w, sc, sh);
    __builtin_nontemporal_store(r, &po[tid + 256]);
    r.x = fmaf(a2.x, sc, sh); r.y = fmaf(a2.y, sc, sh);
    r.z = fmaf(a2.z, sc, sh); r.w = fmaf(a2.w, sc, sh);
    __builtin_nontemporal_store(r, &po[tid + 512]);
    if (tid < 16) {
        r.x = fmaf(a3.x, sc, sh); r.y = fmaf(a3.y, sc, sh);
        r.z = fmaf(a3.z, sc, sh); r.w = fmaf(a3.w, sc, sh);
        __builtin_nontemporal_store(r, &po[tid + 768]);
    }
}

extern "C" void kernel_launch(void* const* d_in, const int* in_sizes, int n_in,
                              void* d_out, int out_size, void* d_ws, size_t ws_size,
                              hipStream_t stream) {
    const float* x       = (const float*)d_in[0];
    const float* alpha_w = (const float*)d_in[2];
    const float* alpha_b = (const float*)d_in[3];
    const float* g_w     = (const float*)d_in[4];
    const float* g_b     = (const float*)d_in[5];
    const float* g_rm    = (const float*)d_in[6];
    const float* g_rv    = (const float*)d_in[7];
    const float* grp_w   = (const float*)d_in[8];
    const float* grp_b   = (const float*)d_in[9];
    const float* grp_rm  = (const float*)d_in[10];
    const float* grp_rv  = (const float*)d_in[11];
    float* out = (float*)d_out;
    float* ws  = (float*)d_ws;

    pool_kernel<<<B_ * C_, 256, 0, stream>>>(x, alpha_w,
                                             g_w, g_b, g_rm, g_rv,
                                             grp_w, grp_b, grp_rm, grp_rv, ws);
    apply_kernel<<<B_ * C_, 256, 0, stream>>>(x, ws, alpha_b, out);
}